// Round 1
// baseline (254.297 us; speedup 1.0000x reference)
//
#include <hip/hip_runtime.h>
#include <math.h>

#define OWN_DIM 7
#define INTR_DIM 5
#define N_HEADS 3
#define HEAD_DIM 5
#define N_INTR 256
#define HID 256
#define BATCH 16384
#define ROW 1287  // OWN_DIM + N_INTR*INTR_DIM

__device__ __forceinline__ float fast_tanh(float x) {
    // tanh(x) = 1 - 2/(exp(2x)+1); exact at +-inf, ~1e-6 abs err
    float e = __expf(2.0f * x);
    return 1.0f - 2.0f * __builtin_amdgcn_rcpf(e + 1.0f);
}

__device__ __forceinline__ float leaky(float x) {
    return x > 0.0f ? x : 0.2f * x;
}

// Kernel 1: attention + W1 -> h1 (B x 256 fp32)
// One wave (64 lanes) per batch row; each lane handles 4 interactions.
__global__ __launch_bounds__(256) void attn_w1_kernel(
    const float* __restrict__ obs,
    const float* __restrict__ Wq, const float* __restrict__ bq,
    const float* __restrict__ Wk, const float* __restrict__ bk,
    const float* __restrict__ Wv, const float* __restrict__ bv,
    const float* __restrict__ v_att, const float* __restrict__ temperature,
    const float* __restrict__ W1, const float* __restrict__ b1,
    float* __restrict__ h1)
{
    __shared__ float w1s[22 * 256];
    int tid = threadIdx.x;
    for (int i = tid; i < 22 * 256; i += 256) w1s[i] = W1[i];
    __syncthreads();

    int wave = tid >> 6;
    int lane = tid & 63;
    int b = blockIdx.x * 4 + wave;
    const float* row = obs + (size_t)b * ROW;

    float absT = fabsf(temperature[0]);

    float own[7];
    #pragma unroll
    for (int o = 0; o < 7; o++) own[o] = row[o];

    // q[h,d] = bq + sum_o own[o]*Wq[h,d,o]
    float q[15];
    #pragma unroll
    for (int hd = 0; hd < 15; hd++) {
        float acc = bq[hd];
        #pragma unroll
        for (int o = 0; o < 7; o++) acc = fmaf(own[o], Wq[hd * 7 + o], acc);
        q[hd] = acc;
    }

    // per-lane: 4 interactions n = lane + 64*j
    float it[4][5];
    float sc[3][4];
    #pragma unroll
    for (int j = 0; j < 4; j++) {
        int n = lane + 64 * j;
        const float* ip = row + OWN_DIM + INTR_DIM * n;
        float asum = 0.0f;
        #pragma unroll
        for (int i = 0; i < 5; i++) { it[j][i] = ip[i]; asum += fabsf(it[j][i]); }
        bool pad = asum < 1e-6f;
        #pragma unroll
        for (int h = 0; h < 3; h++) {
            float s = 0.0f;
            #pragma unroll
            for (int d = 0; d < 5; d++) {
                float kd = bk[h * 5 + d];
                #pragma unroll
                for (int i = 0; i < 5; i++)
                    kd = fmaf(it[j][i], Wk[(h * 5 + d) * 5 + i], kd);
                float e = fast_tanh(q[h * 5 + d] + kd);
                s = fmaf(v_att[h * 5 + d], e, s);
            }
            sc[h][j] = pad ? -INFINITY : s * absT;
        }
    }

    // softmax over 256 (4 per lane x 64 lanes), per head
    float alpha[3][4];
    float sa[3];
    #pragma unroll
    for (int h = 0; h < 3; h++) {
        float m = fmaxf(fmaxf(sc[h][0], sc[h][1]), fmaxf(sc[h][2], sc[h][3]));
        #pragma unroll
        for (int off = 32; off >= 1; off >>= 1) m = fmaxf(m, __shfl_xor(m, off));
        if (m < -3.0e38f) m = 0.0f;  // all-padded guard
        float lsum = 0.0f;
        #pragma unroll
        for (int j = 0; j < 4; j++) { alpha[h][j] = __expf(sc[h][j] - m); lsum += alpha[h][j]; }
        #pragma unroll
        for (int off = 32; off >= 1; off >>= 1) lsum += __shfl_xor(lsum, off);
        float rden = lsum > 0.0f ? __builtin_amdgcn_rcpf(lsum) : 0.0f;
        sa[h] = lsum > 0.0f ? 1.0f : 0.0f;
        #pragma unroll
        for (int j = 0; j < 4; j++) alpha[h][j] *= rden;
    }

    // ctx[h,i] = sum_n alpha[h,n] * intr[n,i]   (v folded: context = Wv.ctx + bv*sum_alpha)
    float ctx[15];
    #pragma unroll
    for (int hi = 0; hi < 15; hi++) ctx[hi] = 0.0f;
    #pragma unroll
    for (int h = 0; h < 3; h++)
        #pragma unroll
        for (int j = 0; j < 4; j++) {
            float a = alpha[h][j];
            #pragma unroll
            for (int i = 0; i < 5; i++)
                ctx[h * 5 + i] = fmaf(a, it[j][i], ctx[h * 5 + i]);
        }
    #pragma unroll
    for (int hi = 0; hi < 15; hi++) {
        float v = ctx[hi];
        #pragma unroll
        for (int off = 32; off >= 1; off >>= 1) v += __shfl_xor(v, off);
        ctx[hi] = v;
    }

    // x = [own(7), context(15)]
    float x[22];
    #pragma unroll
    for (int o = 0; o < 7; o++) x[o] = own[o];
    #pragma unroll
    for (int hd = 0; hd < 15; hd++) {
        int h = hd / 5;
        float acc = bv[hd] * sa[h];
        #pragma unroll
        for (int i = 0; i < 5; i++)
            acc = fmaf(Wv[hd * 5 + i], ctx[h * 5 + i], acc);
        x[7 + hd] = acc;
    }

    // h1[c] = leaky(x @ W1 + b1), lane handles columns 4*lane..4*lane+3
    const float4* b1v = (const float4*)b1;
    float4 bb = b1v[lane];
    float accs[4] = { bb.x, bb.y, bb.z, bb.w };
    #pragma unroll
    for (int i = 0; i < 22; i++) {
        const float4 w = *((const float4*)(w1s + i * 256 + 4 * lane));
        accs[0] = fmaf(x[i], w.x, accs[0]);
        accs[1] = fmaf(x[i], w.y, accs[1]);
        accs[2] = fmaf(x[i], w.z, accs[2]);
        accs[3] = fmaf(x[i], w.w, accs[3]);
    }
    float4 outv;
    outv.x = leaky(accs[0]);
    outv.y = leaky(accs[1]);
    outv.z = leaky(accs[2]);
    outv.w = leaky(accs[3]);
    *((float4*)(h1 + (size_t)b * 256 + 4 * lane)) = outv;
}

// Kernel 2: h2 = leaky(h1 @ W2 + b2); out = [h2 @ Wf + bf, log_std]
// BM=32 rows per block; thread = one of 256 columns, accumulates 32 rows.
#define BM 32
#define ASTRIDE 260  // 32-float-bank-friendly, 16B-aligned row stride

__global__ __launch_bounds__(256) void mlp_kernel(
    const float* __restrict__ h1, const float* __restrict__ W2,
    const float* __restrict__ b2, const float* __restrict__ Wf,
    const float* __restrict__ bf, const float* __restrict__ log_std,
    float* __restrict__ out)
{
    __shared__ float as[BM * ASTRIDE];
    __shared__ float wfs[512];
    int tid = threadIdx.x;
    int b0 = blockIdx.x * BM;

    // stage A tile (32 x 256) as float4
    const float4* h1v = (const float4*)(h1 + (size_t)b0 * 256);
    for (int idx = tid; idx < BM * 64; idx += 256) {
        int r = idx >> 6;
        int k4 = idx & 63;
        float4 v = h1v[idx];
        *((float4*)(as + r * ASTRIDE + k4 * 4)) = v;
    }
    for (int i = tid; i < 512; i += 256) wfs[i] = Wf[i];
    __syncthreads();

    int j = tid;
    float acc[BM];
    #pragma unroll
    for (int r = 0; r < BM; r++) acc[r] = 0.0f;

    for (int k = 0; k < 256; k += 4) {
        float w0 = W2[(k + 0) * 256 + j];
        float w1 = W2[(k + 1) * 256 + j];
        float w2 = W2[(k + 2) * 256 + j];
        float w3 = W2[(k + 3) * 256 + j];
        #pragma unroll
        for (int r = 0; r < BM; r++) {
            const float4 a = *((const float4*)(as + r * ASTRIDE + k));
            acc[r] = fmaf(a.x, w0, acc[r]);
            acc[r] = fmaf(a.y, w1, acc[r]);
            acc[r] = fmaf(a.z, w2, acc[r]);
            acc[r] = fmaf(a.w, w3, acc[r]);
        }
    }

    float bj = b2[j];
    __syncthreads();
    #pragma unroll
    for (int r = 0; r < BM; r++) {
        as[r * ASTRIDE + j] = leaky(acc[r] + bj);
    }
    __syncthreads();

    // epilogue: 64 threads, each computes one (row, act) output pair
    if (tid < 64) {
        int r = tid >> 1;
        int c = tid & 1;
        float s = 0.0f;
        for (int jj = 0; jj < 256; jj++) {
            int jx = (jj + tid) & 255;  // stagger to avoid bank conflicts
            s = fmaf(as[r * ASTRIDE + jx], wfs[jx * 2 + c], s);
        }
        size_t ob = (size_t)(b0 + r) * 4;
        out[ob + c] = s + bf[c];
        out[ob + 2 + c] = log_std[c];
    }
}

extern "C" void kernel_launch(void* const* d_in, const int* in_sizes, int n_in,
                              void* d_out, int out_size, void* d_ws, size_t ws_size,
                              hipStream_t stream) {
    const float* obs  = (const float*)d_in[0];
    const float* Wq   = (const float*)d_in[1];
    const float* bq   = (const float*)d_in[2];
    const float* Wk   = (const float*)d_in[3];
    const float* bk   = (const float*)d_in[4];
    const float* Wv   = (const float*)d_in[5];
    const float* bv   = (const float*)d_in[6];
    const float* v_att = (const float*)d_in[7];
    const float* temperature = (const float*)d_in[8];
    const float* W1   = (const float*)d_in[9];
    const float* b1   = (const float*)d_in[10];
    const float* W2   = (const float*)d_in[11];
    const float* b2   = (const float*)d_in[12];
    const float* Wf   = (const float*)d_in[13];
    const float* bf   = (const float*)d_in[14];
    const float* log_std = (const float*)d_in[15];
    float* out = (float*)d_out;

    float* h1 = (float*)d_ws;  // B x 256 fp32 = 16 MB

    attn_w1_kernel<<<BATCH / 4, 256, 0, stream>>>(
        obs, Wq, bq, Wk, bk, Wv, bv, v_att, temperature, W1, b1, h1);
    mlp_kernel<<<BATCH / BM, 256, 0, stream>>>(
        h1, W2, b2, Wf, bf, log_std, out);
}

// Round 2
// 196.150 us; speedup vs baseline: 1.2964x; 1.2964x over previous
//
#include <hip/hip_runtime.h>
#include <math.h>

#define OWN_DIM 7
#define INTR_DIM 5
#define N_HEADS 3
#define HEAD_DIM 5
#define N_INTR 256
#define HID 256
#define BATCH 16384
#define ROW 1287  // OWN_DIM + N_INTR*INTR_DIM

typedef __attribute__((ext_vector_type(8))) short bf16x8;
typedef __attribute__((ext_vector_type(4))) float f32x4;

__device__ __forceinline__ float fast_tanh(float x) {
    float e = __expf(2.0f * x);
    return 1.0f - 2.0f * __builtin_amdgcn_rcpf(e + 1.0f);
}

__device__ __forceinline__ float leaky(float x) {
    return x > 0.0f ? x : 0.2f * x;
}

__device__ __forceinline__ unsigned short f2bf(float f) {
    union { float f; unsigned u; } v; v.f = f;
    unsigned r = (v.u + 0x7FFFu + ((v.u >> 16) & 1u)) >> 16;
    return (unsigned short)r;
}

__device__ __forceinline__ float bf2f(unsigned short s) {
    union { unsigned u; float f; } v; v.u = ((unsigned)s) << 16;
    return v.f;
}

// Kernel 1: attention + W1 -> h1 (B x 256 bf16)
__global__ __launch_bounds__(256) void attn_w1_kernel(
    const float* __restrict__ obs,
    const float* __restrict__ Wq, const float* __restrict__ bq,
    const float* __restrict__ Wk, const float* __restrict__ bk,
    const float* __restrict__ Wv, const float* __restrict__ bv,
    const float* __restrict__ v_att, const float* __restrict__ temperature,
    const float* __restrict__ W1, const float* __restrict__ b1,
    unsigned short* __restrict__ h1b)
{
    __shared__ float w1s[22 * 256];
    int tid = threadIdx.x;
    for (int i = tid; i < 22 * 256; i += 256) w1s[i] = W1[i];
    __syncthreads();

    int wave = tid >> 6;
    int lane = tid & 63;
    int b = blockIdx.x * 4 + wave;
    const float* row = obs + (size_t)b * ROW;

    float absT = fabsf(temperature[0]);

    float own[7];
    #pragma unroll
    for (int o = 0; o < 7; o++) own[o] = row[o];

    float q[15];
    #pragma unroll
    for (int hd = 0; hd < 15; hd++) {
        float acc = bq[hd];
        #pragma unroll
        for (int o = 0; o < 7; o++) acc = fmaf(own[o], Wq[hd * 7 + o], acc);
        q[hd] = acc;
    }

    float it[4][5];
    float sc[3][4];
    #pragma unroll
    for (int j = 0; j < 4; j++) {
        int n = lane + 64 * j;
        const float* ip = row + OWN_DIM + INTR_DIM * n;
        float asum = 0.0f;
        #pragma unroll
        for (int i = 0; i < 5; i++) { it[j][i] = ip[i]; asum += fabsf(it[j][i]); }
        bool pad = asum < 1e-6f;
        #pragma unroll
        for (int h = 0; h < 3; h++) {
            float s = 0.0f;
            #pragma unroll
            for (int d = 0; d < 5; d++) {
                float kd = bk[h * 5 + d];
                #pragma unroll
                for (int i = 0; i < 5; i++)
                    kd = fmaf(it[j][i], Wk[(h * 5 + d) * 5 + i], kd);
                float e = fast_tanh(q[h * 5 + d] + kd);
                s = fmaf(v_att[h * 5 + d], e, s);
            }
            sc[h][j] = pad ? -INFINITY : s * absT;
        }
    }

    float alpha[3][4];
    float sa[3];
    #pragma unroll
    for (int h = 0; h < 3; h++) {
        float m = fmaxf(fmaxf(sc[h][0], sc[h][1]), fmaxf(sc[h][2], sc[h][3]));
        #pragma unroll
        for (int off = 32; off >= 1; off >>= 1) m = fmaxf(m, __shfl_xor(m, off));
        if (m < -3.0e38f) m = 0.0f;
        float lsum = 0.0f;
        #pragma unroll
        for (int j = 0; j < 4; j++) { alpha[h][j] = __expf(sc[h][j] - m); lsum += alpha[h][j]; }
        #pragma unroll
        for (int off = 32; off >= 1; off >>= 1) lsum += __shfl_xor(lsum, off);
        float rden = lsum > 0.0f ? __builtin_amdgcn_rcpf(lsum) : 0.0f;
        sa[h] = lsum > 0.0f ? 1.0f : 0.0f;
        #pragma unroll
        for (int j = 0; j < 4; j++) alpha[h][j] *= rden;
    }

    float ctx[15];
    #pragma unroll
    for (int hi = 0; hi < 15; hi++) ctx[hi] = 0.0f;
    #pragma unroll
    for (int h = 0; h < 3; h++)
        #pragma unroll
        for (int j = 0; j < 4; j++) {
            float a = alpha[h][j];
            #pragma unroll
            for (int i = 0; i < 5; i++)
                ctx[h * 5 + i] = fmaf(a, it[j][i], ctx[h * 5 + i]);
        }
    #pragma unroll
    for (int hi = 0; hi < 15; hi++) {
        float v = ctx[hi];
        #pragma unroll
        for (int off = 32; off >= 1; off >>= 1) v += __shfl_xor(v, off);
        ctx[hi] = v;
    }

    float x[22];
    #pragma unroll
    for (int o = 0; o < 7; o++) x[o] = own[o];
    #pragma unroll
    for (int hd = 0; hd < 15; hd++) {
        int h = hd / 5;
        float acc = bv[hd] * sa[h];
        #pragma unroll
        for (int i = 0; i < 5; i++)
            acc = fmaf(Wv[hd * 5 + i], ctx[h * 5 + i], acc);
        x[7 + hd] = acc;
    }

    const float4* b1v = (const float4*)b1;
    float4 bb = b1v[lane];
    float accs[4] = { bb.x, bb.y, bb.z, bb.w };
    #pragma unroll
    for (int i = 0; i < 22; i++) {
        const float4 w = *((const float4*)(w1s + i * 256 + 4 * lane));
        accs[0] = fmaf(x[i], w.x, accs[0]);
        accs[1] = fmaf(x[i], w.y, accs[1]);
        accs[2] = fmaf(x[i], w.z, accs[2]);
        accs[3] = fmaf(x[i], w.w, accs[3]);
    }
    ushort4 outv;
    outv.x = f2bf(leaky(accs[0]));
    outv.y = f2bf(leaky(accs[1]));
    outv.z = f2bf(leaky(accs[2]));
    outv.w = f2bf(leaky(accs[3]));
    *((ushort4*)(h1b + (size_t)b * 256 + 4 * lane)) = outv;
}

// Kernel 2: h2 = leaky(h1 @ W2 + b2) via bf16 MFMA, h2 stored bf16.
// Grid (4, 128): blockIdx.x = n-group (64 cols), blockIdx.y = m-chunk (128 rows).
// Each wave owns one 16-col strip; B-frags (W2 strip) held in registers for
// the whole K=256; loops 8 m-tiles of 16 rows, A-frags loaded from global.
__global__ __launch_bounds__(256) void mlp_mfma_kernel(
    const unsigned short* __restrict__ h1b, const float* __restrict__ W2,
    const float* __restrict__ b2, unsigned short* __restrict__ h2b)
{
    int tid = threadIdx.x;
    int wave = tid >> 6;
    int lane = tid & 63;
    int lm = lane & 15;   // n within strip (B), m within tile (A), col (C)
    int q  = lane >> 4;   // quad

    int n0 = blockIdx.x * 64 + wave * 16;
    int m_base = blockIdx.y * 128;

    // B fragments: bfrag[s] element j = bf16(W2[(s*32 + q*8 + j)*256 + n0+lm])
    bf16x8 bfrag[8];
    #pragma unroll
    for (int s = 0; s < 8; s++) {
        #pragma unroll
        for (int j = 0; j < 8; j++) {
            int k = s * 32 + q * 8 + j;
            bfrag[s][j] = (short)f2bf(W2[k * 256 + n0 + lm]);
        }
    }

    float bias = b2[n0 + lm];

    #pragma unroll
    for (int mt = 0; mt < 8; mt++) {
        int m0 = m_base + mt * 16;
        const unsigned short* arow = h1b + (size_t)(m0 + lm) * 256 + q * 8;

        f32x4 acc = {0.0f, 0.0f, 0.0f, 0.0f};
        #pragma unroll
        for (int s = 0; s < 8; s++) {
            bf16x8 afrag = *((const bf16x8*)(arow + s * 32));
            acc = __builtin_amdgcn_mfma_f32_16x16x32_bf16(afrag, bfrag[s], acc, 0, 0, 0);
        }
        // C: row = m0 + q*4 + i, col = n0 + lm
        #pragma unroll
        for (int i = 0; i < 4; i++) {
            int r = m0 + q * 4 + i;
            h2b[(size_t)r * 256 + n0 + lm] = f2bf(leaky(acc[i] + bias));
        }
    }
}

// Kernel 3: out[b] = [h2[b] @ Wf + bf, log_std]; one thread per batch row.
__global__ __launch_bounds__(256) void final_kernel(
    const unsigned short* __restrict__ h2b, const float* __restrict__ Wf,
    const float* __restrict__ bf, const float* __restrict__ log_std,
    float* __restrict__ out)
{
    __shared__ float wfs[512];
    int tid = threadIdx.x;
    for (int i = tid; i < 512; i += 256) wfs[i] = Wf[i];
    __syncthreads();

    int b = blockIdx.x * 256 + tid;
    const uint4* hv = (const uint4*)(h2b + (size_t)b * 256);

    float a0 = 0.0f, a1 = 0.0f;
    #pragma unroll 4
    for (int jj = 0; jj < 32; jj++) {
        uint4 u = hv[jj];
        unsigned w[4] = { u.x, u.y, u.z, u.w };
        #pragma unroll
        for (int p = 0; p < 4; p++) {
            float lo = bf2f((unsigned short)(w[p] & 0xFFFFu));
            float hi = bf2f((unsigned short)(w[p] >> 16));
            int j = jj * 8 + p * 2;
            a0 = fmaf(lo, wfs[(j + 0) * 2 + 0], a0);
            a1 = fmaf(lo, wfs[(j + 0) * 2 + 1], a1);
            a0 = fmaf(hi, wfs[(j + 1) * 2 + 0], a0);
            a1 = fmaf(hi, wfs[(j + 1) * 2 + 1], a1);
        }
    }
    float4 o;
    o.x = a0 + bf[0];
    o.y = a1 + bf[1];
    o.z = log_std[0];
    o.w = log_std[1];
    *((float4*)(out + (size_t)b * 4)) = o;
}

extern "C" void kernel_launch(void* const* d_in, const int* in_sizes, int n_in,
                              void* d_out, int out_size, void* d_ws, size_t ws_size,
                              hipStream_t stream) {
    const float* obs  = (const float*)d_in[0];
    const float* Wq   = (const float*)d_in[1];
    const float* bq   = (const float*)d_in[2];
    const float* Wk   = (const float*)d_in[3];
    const float* bk   = (const float*)d_in[4];
    const float* Wv   = (const float*)d_in[5];
    const float* bv   = (const float*)d_in[6];
    const float* v_att = (const float*)d_in[7];
    const float* temperature = (const float*)d_in[8];
    const float* W1   = (const float*)d_in[9];
    const float* b1   = (const float*)d_in[10];
    const float* W2   = (const float*)d_in[11];
    const float* b2   = (const float*)d_in[12];
    const float* Wf   = (const float*)d_in[13];
    const float* bf   = (const float*)d_in[14];
    const float* log_std = (const float*)d_in[15];
    float* out = (float*)d_out;

    unsigned short* h1b = (unsigned short*)d_ws;                       // 8 MiB
    unsigned short* h2b = h1b + (size_t)BATCH * 256;                   // 8 MiB

    attn_w1_kernel<<<BATCH / 4, 256, 0, stream>>>(
        obs, Wq, bq, Wk, bk, Wv, bv, v_att, temperature, W1, b1, h1b);
    mlp_mfma_kernel<<<dim3(4, 128), 256, 0, stream>>>(h1b, W2, b2, h2b);
    final_kernel<<<BATCH / 256, 256, 0, stream>>>(h2b, Wf, bf, log_std, out);
}

// Round 3
// 185.535 us; speedup vs baseline: 1.3706x; 1.0572x over previous
//
#include <hip/hip_runtime.h>
#include <math.h>

#define OWN_DIM 7
#define INTR_DIM 5
#define N_HEADS 3
#define HEAD_DIM 5
#define N_INTR 256
#define HID 256
#define BATCH 16384
#define ROW 1287  // OWN_DIM + N_INTR*INTR_DIM

typedef __attribute__((ext_vector_type(8))) short bf16x8;
typedef __attribute__((ext_vector_type(4))) float f32x4;

__device__ __forceinline__ float fast_tanh(float x) {
    float e = __expf(2.0f * x);
    return 1.0f - 2.0f * __builtin_amdgcn_rcpf(e + 1.0f);
}

__device__ __forceinline__ float leaky(float x) {
    return x > 0.0f ? x : 0.2f * x;
}

__device__ __forceinline__ unsigned short f2bf(float f) {
    union { float f; unsigned u; } v; v.f = f;
    unsigned r = (v.u + 0x7FFFu + ((v.u >> 16) & 1u)) >> 16;
    return (unsigned short)r;
}

__device__ __forceinline__ unsigned pack2(unsigned short a, unsigned short b) {
    return (unsigned)a | ((unsigned)b << 16);
}

// Prep: W1 (22x256 f32) -> W1t (256x32 bf16, col-major, zero-padded K);
//       W2 (256x256 f32) -> W2t (256x256 bf16, col-major).
__global__ __launch_bounds__(256) void prep_kernel(
    const float* __restrict__ W1, const float* __restrict__ W2,
    unsigned short* __restrict__ W1t, unsigned short* __restrict__ W2t)
{
    int idx = blockIdx.x * 256 + threadIdx.x;   // 0..16383
    int col = idx & 255;
    int kq = idx >> 8;                          // 0..63
    ushort4 o;
    o.x = f2bf(W2[(kq * 4 + 0) * 256 + col]);
    o.y = f2bf(W2[(kq * 4 + 1) * 256 + col]);
    o.z = f2bf(W2[(kq * 4 + 2) * 256 + col]);
    o.w = f2bf(W2[(kq * 4 + 3) * 256 + col]);
    *((ushort4*)(W2t + col * 256 + kq * 4)) = o;
    if (kq < 8) {
        ushort4 p;
        int k = kq * 4;
        p.x = (k + 0) < 22 ? f2bf(W1[(k + 0) * 256 + col]) : 0;
        p.y = (k + 1) < 22 ? f2bf(W1[(k + 1) * 256 + col]) : 0;
        p.z = (k + 2) < 22 ? f2bf(W1[(k + 2) * 256 + col]) : 0;
        p.w = (k + 3) < 22 ? f2bf(W1[(k + 3) * 256 + col]) : 0;
        *((ushort4*)(W1t + col * 32 + k)) = p;
    }
}

// Kernel 1: attention -> x (B x 32 bf16: [own(7), context(15), zeros(10)])
__global__ __launch_bounds__(256) void attn_kernel(
    const float* __restrict__ obs,
    const float* __restrict__ Wq, const float* __restrict__ bq,
    const float* __restrict__ Wk, const float* __restrict__ bk,
    const float* __restrict__ Wv, const float* __restrict__ bv,
    const float* __restrict__ v_att, const float* __restrict__ temperature,
    unsigned short* __restrict__ xb)
{
    int tid = threadIdx.x;
    int wave = tid >> 6;
    int lane = tid & 63;
    int b = blockIdx.x * 4 + wave;
    const float* row = obs + (size_t)b * ROW;

    float absT = fabsf(temperature[0]);

    float own[7];
    #pragma unroll
    for (int o = 0; o < 7; o++) own[o] = row[o];

    float q[15];
    #pragma unroll
    for (int hd = 0; hd < 15; hd++) {
        float acc = bq[hd];
        #pragma unroll
        for (int o = 0; o < 7; o++) acc = fmaf(own[o], Wq[hd * 7 + o], acc);
        q[hd] = acc;
    }

    float it[4][5];
    float sc[3][4];
    #pragma unroll
    for (int j = 0; j < 4; j++) {
        int n = lane + 64 * j;
        const float* ip = row + OWN_DIM + INTR_DIM * n;
        float4 v4;
        __builtin_memcpy(&v4, ip, 16);
        it[j][0] = v4.x; it[j][1] = v4.y; it[j][2] = v4.z; it[j][3] = v4.w;
        it[j][4] = ip[4];
        float asum = 0.0f;
        #pragma unroll
        for (int i = 0; i < 5; i++) asum += fabsf(it[j][i]);
        bool pad = asum < 1e-6f;
        #pragma unroll
        for (int h = 0; h < 3; h++) {
            float s = 0.0f;
            #pragma unroll
            for (int d = 0; d < 5; d++) {
                float kd = bk[h * 5 + d];
                #pragma unroll
                for (int i = 0; i < 5; i++)
                    kd = fmaf(it[j][i], Wk[(h * 5 + d) * 5 + i], kd);
                float e = fast_tanh(q[h * 5 + d] + kd);
                s = fmaf(v_att[h * 5 + d], e, s);
            }
            sc[h][j] = pad ? -INFINITY : s * absT;
        }
    }

    float alpha[3][4];
    float sa[3];
    #pragma unroll
    for (int h = 0; h < 3; h++) {
        float m = fmaxf(fmaxf(sc[h][0], sc[h][1]), fmaxf(sc[h][2], sc[h][3]));
        #pragma unroll
        for (int off = 32; off >= 1; off >>= 1) m = fmaxf(m, __shfl_xor(m, off));
        if (m < -3.0e38f) m = 0.0f;
        float lsum = 0.0f;
        #pragma unroll
        for (int j = 0; j < 4; j++) { alpha[h][j] = __expf(sc[h][j] - m); lsum += alpha[h][j]; }
        #pragma unroll
        for (int off = 32; off >= 1; off >>= 1) lsum += __shfl_xor(lsum, off);
        float rden = lsum > 0.0f ? __builtin_amdgcn_rcpf(lsum) : 0.0f;
        sa[h] = lsum > 0.0f ? 1.0f : 0.0f;
        #pragma unroll
        for (int j = 0; j < 4; j++) alpha[h][j] *= rden;
    }

    float ctx[15];
    #pragma unroll
    for (int hi = 0; hi < 15; hi++) ctx[hi] = 0.0f;
    #pragma unroll
    for (int h = 0; h < 3; h++)
        #pragma unroll
        for (int j = 0; j < 4; j++) {
            float a = alpha[h][j];
            #pragma unroll
            for (int i = 0; i < 5; i++)
                ctx[h * 5 + i] = fmaf(a, it[j][i], ctx[h * 5 + i]);
        }
    #pragma unroll
    for (int hi = 0; hi < 15; hi++) {
        float v = ctx[hi];
        #pragma unroll
        for (int off = 32; off >= 1; off >>= 1) v += __shfl_xor(v, off);
        ctx[hi] = v;
    }

    float x[22];
    #pragma unroll
    for (int o = 0; o < 7; o++) x[o] = own[o];
    #pragma unroll
    for (int hd = 0; hd < 15; hd++) {
        int h = hd / 5;
        float acc = bv[hd] * sa[h];
        #pragma unroll
        for (int i = 0; i < 5; i++)
            acc = fmaf(Wv[hd * 5 + i], ctx[h * 5 + i], acc);
        x[7 + hd] = acc;
    }

    // pack to bf16 (constant indices), lanes 0-3 store 16B each -> 64B row
    unsigned short xs[24];
    #pragma unroll
    for (int i = 0; i < 22; i++) xs[i] = f2bf(x[i]);
    xs[22] = 0; xs[23] = 0;
    uint4 u0 = { pack2(xs[0], xs[1]),  pack2(xs[2], xs[3]),  pack2(xs[4], xs[5]),  pack2(xs[6], xs[7]) };
    uint4 u1 = { pack2(xs[8], xs[9]),  pack2(xs[10], xs[11]), pack2(xs[12], xs[13]), pack2(xs[14], xs[15]) };
    uint4 u2 = { pack2(xs[16], xs[17]), pack2(xs[18], xs[19]), pack2(xs[20], xs[21]), pack2(xs[22], xs[23]) };
    uint4 u3 = { 0u, 0u, 0u, 0u };
    uint4 lo = (lane & 1) ? u1 : u0;
    uint4 hi = (lane & 1) ? u3 : u2;
    uint4 sel = (lane & 2) ? hi : lo;
    if (lane < 4) {
        *((uint4*)(xb + (size_t)b * 32 + lane * 8)) = sel;
    }
}

// Kernel 2: fused MLP. x -> h1 (W1 mfma, LDS) -> h2 (W2 mfma) -> Wf dot -> out.
// Block: 256 thr / 4 waves; wave owns 64 W2-cols (4 strips of 16).
// Tile: 32 rows (2 subtiles of 16). Grid: 512.
__global__ __launch_bounds__(256, 2) void mlp_fused_kernel(
    const unsigned short* __restrict__ xb,
    const unsigned short* __restrict__ W1t, const unsigned short* __restrict__ W2t,
    const float* __restrict__ b1, const float* __restrict__ b2,
    const float* __restrict__ Wf, const float* __restrict__ bfv,
    const float* __restrict__ log_std, float* __restrict__ out)
{
    __shared__ unsigned short h1t[16 * 264];   // 16 rows x 264 bf16 (pad 8)
    __shared__ float finbuf[2][4][16][2];      // parity, wave, row, act

    int tid = threadIdx.x;
    int w = tid >> 6;
    int lane = tid & 63;
    int lm = lane & 15;
    int q = lane >> 4;
    int mbase = blockIdx.x * 32;

    float b1v[4], b2v[4], wf0[4], wf1[4];
    bf16x8 fw1[4];
    bf16x8 fw2[4][8];
    #pragma unroll
    for (int s = 0; s < 4; s++) {
        int col = w * 64 + s * 16 + lm;
        b1v[s] = b1[col];
        b2v[s] = b2[col];
        wf0[s] = Wf[col * 2];
        wf1[s] = Wf[col * 2 + 1];
        fw1[s] = *((const bf16x8*)(W1t + col * 32 + q * 8));
        #pragma unroll
        for (int t = 0; t < 8; t++)
            fw2[s][t] = *((const bf16x8*)(W2t + col * 256 + t * 32 + q * 8));
    }

    #pragma unroll
    for (int mt = 0; mt < 2; mt++) {
        int m0 = mbase + mt * 16;
        bf16x8 ax = *((const bf16x8*)(xb + (size_t)(m0 + lm) * 32 + q * 8));

        // W1 stage: h1 tile (16 x 256) into LDS
        #pragma unroll
        for (int s = 0; s < 4; s++) {
            f32x4 c = {0.0f, 0.0f, 0.0f, 0.0f};
            c = __builtin_amdgcn_mfma_f32_16x16x32_bf16(ax, fw1[s], c, 0, 0, 0);
            int col = w * 64 + s * 16 + lm;
            #pragma unroll
            for (int i = 0; i < 4; i++)
                h1t[(q * 4 + i) * 264 + col] = f2bf(leaky(c[i] + b1v[s]));
        }
        __syncthreads();

        // W2 stage
        bf16x8 a2[8];
        #pragma unroll
        for (int t = 0; t < 8; t++)
            a2[t] = *((const bf16x8*)(h1t + lm * 264 + t * 32 + q * 8));

        float p0[4] = {0, 0, 0, 0};
        float p1[4] = {0, 0, 0, 0};
        #pragma unroll
        for (int s = 0; s < 4; s++) {
            f32x4 acc = {0.0f, 0.0f, 0.0f, 0.0f};
            #pragma unroll
            for (int t = 0; t < 8; t++)
                acc = __builtin_amdgcn_mfma_f32_16x16x32_bf16(a2[t], fw2[s][t], acc, 0, 0, 0);
            #pragma unroll
            for (int i = 0; i < 4; i++) {
                float h2 = leaky(acc[i] + b2v[s]);
                p0[i] = fmaf(h2, wf0[s], p0[i]);
                p1[i] = fmaf(h2, wf1[s], p1[i]);
            }
        }

        // reduce over the 16 cols (lm) of each strip-group
        #pragma unroll
        for (int off = 1; off < 16; off <<= 1) {
            #pragma unroll
            for (int i = 0; i < 4; i++) {
                p0[i] += __shfl_xor(p0[i], off);
                p1[i] += __shfl_xor(p1[i], off);
            }
        }
        if (lm == 0) {
            #pragma unroll
            for (int i = 0; i < 4; i++) {
                finbuf[mt][w][q * 4 + i][0] = p0[i];
                finbuf[mt][w][q * 4 + i][1] = p1[i];
            }
        }
        __syncthreads();
        if (tid < 32) {
            int r = tid >> 1;
            int a = tid & 1;
            float s4 = finbuf[mt][0][r][a] + finbuf[mt][1][r][a]
                     + finbuf[mt][2][r][a] + finbuf[mt][3][r][a];
            out[(size_t)(m0 + r) * 4 + a] = s4 + bfv[a];
            out[(size_t)(m0 + r) * 4 + 2 + a] = log_std[a];
        }
    }
}

extern "C" void kernel_launch(void* const* d_in, const int* in_sizes, int n_in,
                              void* d_out, int out_size, void* d_ws, size_t ws_size,
                              hipStream_t stream) {
    const float* obs  = (const float*)d_in[0];
    const float* Wq   = (const float*)d_in[1];
    const float* bq   = (const float*)d_in[2];
    const float* Wk   = (const float*)d_in[3];
    const float* bk   = (const float*)d_in[4];
    const float* Wv   = (const float*)d_in[5];
    const float* bv   = (const float*)d_in[6];
    const float* v_att = (const float*)d_in[7];
    const float* temperature = (const float*)d_in[8];
    const float* W1   = (const float*)d_in[9];
    const float* b1   = (const float*)d_in[10];
    const float* W2   = (const float*)d_in[11];
    const float* b2   = (const float*)d_in[12];
    const float* Wf   = (const float*)d_in[13];
    const float* bf   = (const float*)d_in[14];
    const float* log_std = (const float*)d_in[15];
    float* out = (float*)d_out;

    unsigned short* xb  = (unsigned short*)d_ws;                        // 1 MiB
    unsigned short* W1t = xb + (size_t)BATCH * 32;                      // 16 KiB
    unsigned short* W2t = W1t + 256 * 32;                               // 128 KiB

    prep_kernel<<<64, 256, 0, stream>>>(W1, W2, W1t, W2t);
    attn_kernel<<<BATCH / 4, 256, 0, stream>>>(
        obs, Wq, bq, Wk, bk, Wv, bv, v_att, temperature, xb);
    mlp_fused_kernel<<<BATCH / 32, 256, 0, stream>>>(
        xb, W1t, W2t, b1, b2, Wf, bf, log_std, out);
}